// Round 5
// baseline (51.993 us; speedup 1.0000x reference)
//
#include <hip/hip_runtime.h>
#include <hip/hip_fp16.h>

#define LN2F 0.69314718055994530942f

// lane l gets lane l-1's v; lane 0 gets fill. VALU DPP, no LDS.
__device__ __forceinline__ float shr1(float v, float fill) {
    return __int_as_float(__builtin_amdgcn_update_dpp(
        __float_as_int(fill), __float_as_int(v), 0x138 /*wave_shr:1*/, 0xF, 0xF, false));
}

// DPP wave-reduce: row_shr 1,2,4,8 then bcast15(0xA), bcast31(0xC).
// Result valid in lane 63 only. All VALU pipe (no ds_bpermute).
__device__ __forceinline__ float wave_max63(float x) {
    int iv = __float_as_int(x); int t;
    t = __builtin_amdgcn_update_dpp(iv, iv, 0x111, 0xF, 0xF, false);
    x = fmaxf(x, __int_as_float(t)); iv = __float_as_int(x);
    t = __builtin_amdgcn_update_dpp(iv, iv, 0x112, 0xF, 0xF, false);
    x = fmaxf(x, __int_as_float(t)); iv = __float_as_int(x);
    t = __builtin_amdgcn_update_dpp(iv, iv, 0x114, 0xF, 0xF, false);
    x = fmaxf(x, __int_as_float(t)); iv = __float_as_int(x);
    t = __builtin_amdgcn_update_dpp(iv, iv, 0x118, 0xF, 0xF, false);
    x = fmaxf(x, __int_as_float(t)); iv = __float_as_int(x);
    t = __builtin_amdgcn_update_dpp(iv, iv, 0x142, 0xA, 0xF, false);
    x = fmaxf(x, __int_as_float(t)); iv = __float_as_int(x);
    t = __builtin_amdgcn_update_dpp(iv, iv, 0x143, 0xC, 0xF, false);
    x = fmaxf(x, __int_as_float(t));
    return x;
}

__device__ __forceinline__ float wave_sum63(float x) {
    int t;
    t = __builtin_amdgcn_update_dpp(0, __float_as_int(x), 0x111, 0xF, 0xF, true);
    x += __int_as_float(t);
    t = __builtin_amdgcn_update_dpp(0, __float_as_int(x), 0x112, 0xF, 0xF, true);
    x += __int_as_float(t);
    t = __builtin_amdgcn_update_dpp(0, __float_as_int(x), 0x114, 0xF, 0xF, true);
    x += __int_as_float(t);
    t = __builtin_amdgcn_update_dpp(0, __float_as_int(x), 0x118, 0xF, 0xF, true);
    x += __int_as_float(t);
    t = __builtin_amdgcn_update_dpp(0, __float_as_int(x), 0x142, 0xA, 0xF, true);
    x += __int_as_float(t);
    t = __builtin_amdgcn_update_dpp(0, __float_as_int(x), 0x143, 0xC, 0xF, true);
    x += __int_as_float(t);
    return x;
}

__device__ __forceinline__ float rdl63(float v) {
    return __int_as_float(__builtin_amdgcn_readlane(__float_as_int(v), 63));
}

// One block per batch, 320 threads. Waves 1-4 stream y_pred -> lse + fp16
// (d1,d3) into a 2x[64][64] LDS chunk ring (16 rows each, UNCONDITIONAL
// loads so all 16 stay in flight); wave 0 runs the serial alpha recursion.
__global__ __launch_bounds__(320) void ctc_fused(const int* __restrict__ yt,
                                                 const float* __restrict__ yp,
                                                 float* __restrict__ loss) {
    constexpr int T = 512, C = 128, L = 128;
    constexpr int CH = 64;
    const int b    = blockIdx.x;
    const int tid  = threadIdx.x;
    const int w    = tid >> 6;       // 0 = consumer, 1..4 = producers
    const int lane = tid & 63;

    __shared__ __half2 gbuf[2][CH][64];   // 32 KB
    __shared__ float   Af[257];
    __shared__ float   accS[5];

    const float* xpb = yp + (size_t)b * T * C;

    // per-lane label classes (lane l owns extended states 4l..4l+3)
    const int2 cc = *reinterpret_cast<const int2*>(yt + b * L + 2 * lane);
    const int c1 = cc.x, c3 = cc.y;
    const int sl1 = c1 >> 1, sh1 = (c1 & 1) << 4;
    const int sl3 = c3 >> 1, sh3 = (c3 & 1) << 4;

    float acc = 0.0f;   // producer: sum of (lse - x_blank) over its rows

    auto produce = [&](int ck) {
        const int sel   = ck & 1;
        const int rbase = (w - 1) * 16;
        const float* src = xpb + ((size_t)ck * CH + rbase) * C + lane * 2;
        float2 v[16];
        #pragma unroll
        for (int i = 0; i < 16; ++i)
            v[i] = *reinterpret_cast<const float2*>(src + i * C);
        #pragma unroll
        for (int i = 0; i < 16; ++i) {
            const float2 vv = v[i];
            const float mall = rdl63(wave_max63(fmaxf(vv.x, vv.y)));
            const float sall = rdl63(wave_sum63(__expf(vv.x - mall) + __expf(vv.y - mall)));
            const float xbv  = rdl63(vv.y);   // class 127 (blank) = lane63.y
            acc += (mall - xbv) + __logf(sall);
            const __half2 hh = __floats2half2_rn(vv.x, vv.y);
            const int hbits = __builtin_bit_cast(int, hh);
            const int g1 = __shfl(hbits, sl1, 64);
            const int g3 = __shfl(hbits, sl3, 64);
            const float x1 = __half2float(__builtin_bit_cast(__half, (unsigned short)(g1 >> sh1)));
            const float x3 = __half2float(__builtin_bit_cast(__half, (unsigned short)(g3 >> sh3)));
            gbuf[sel][rbase + i][lane] = __floats2half2_rn(x1 - xbv, x3 - xbv);
        }
    };

    // consumer state (wave 0): lane l owns s=4l..4l+3; lane63 also s=256 in o4
    float o0 = 0, o1 = 0, o2 = 0, o3 = 0, o4 = 0;
    int   Eacc = 0;
    float sk1 = 0, sk3 = 0;
    int   llen = 0;
    if (w == 0) {
        const int cprev = __shfl_up(c3, 1, 64);
        sk1 = (lane > 0 && c1 != cprev) ? 1.0f : 0.0f;
        sk3 = (c3 != c1) ? 1.0f : 0.0f;
        llen = __popcll(__ballot(c1 != 0)) + __popcll(__ballot(c3 != 0));
    }

#define RENORM()                                                               \
    {                                                                          \
        float mr = fmaxf(fmaxf(fmaxf(o0, o1), fmaxf(o2, o3)), o4);             \
        const float mru = rdl63(wave_max63(mr));                               \
        const int ie = (__float_as_int(mru) >> 23) & 0xFF;                     \
        const float sc = __int_as_float((253 - ie) << 23);                     \
        o0 *= sc; o1 *= sc; o2 *= sc; o3 *= sc; o4 *= sc;                      \
        Eacc += ie - 126;                                                      \
    }

#define CSTEP(bits_, rn_)                                                      \
    {                                                                          \
        const float2 dd = __half22float2(__builtin_bit_cast(__half2, (bits_)));\
        const float e1 = __expf(dd.x);                                         \
        const float e3 = __expf(dd.y);                                         \
        const float pm = shr1(o3, 0.0f);                                       \
        const float n0 = o0 + pm;                                              \
        const float n1 = (o1 + o0 + sk1 * pm) * e1;                            \
        const float n2 = o2 + o1;                                              \
        const float n3 = (o3 + o2 + sk3 * o1) * e3;                            \
        o4 += o3;                                                              \
        o0 = n0; o1 = n1; o2 = n2; o3 = n3;                                    \
        if (rn_) RENORM();                                                     \
    }

    auto consume = [&](const __half2 (*gb)[64], bool first) {
        int A[8], Bv[8];
        #pragma unroll
        for (int j = 0; j < 8; ++j) A[j] = __builtin_bit_cast(int, gb[j][lane]);
        #pragma unroll
        for (int j = 0; j < 8; ++j) Bv[j] = __builtin_bit_cast(int, gb[8 + j][lane]);
        if (first) {   // t=0 init: beta_0 = exp(alpha_0 - x_0[blank])
            const float2 d0 = __half22float2(__builtin_bit_cast(__half2, A[0]));
            o0 = (lane == 0) ? 1.0f : 0.0f;
            o1 = (lane == 0) ? __expf(d0.x) : 0.0f;
            o2 = 0.0f; o3 = 0.0f; o4 = 0.0f;
        } else {
            CSTEP(A[0], true);                       // t = 64k -> renorm
        }
        #pragma unroll
        for (int j = 1; j < 8; ++j) CSTEP(A[j], false);
        #pragma unroll
        for (int j = 0; j < 8; ++j) A[j] = __builtin_bit_cast(int, gb[16 + j][lane]);
        #pragma unroll
        for (int j = 0; j < 8; ++j) CSTEP(Bv[j], false);   // rows 8..15
        #pragma unroll
        for (int j = 0; j < 8; ++j) Bv[j] = __builtin_bit_cast(int, gb[24 + j][lane]);
        #pragma unroll
        for (int j = 0; j < 8; ++j) CSTEP(A[j], false);    // rows 16..23
        #pragma unroll
        for (int j = 0; j < 8; ++j) A[j] = __builtin_bit_cast(int, gb[32 + j][lane]);
        #pragma unroll
        for (int j = 0; j < 8; ++j) CSTEP(Bv[j], false);   // rows 24..31
        #pragma unroll
        for (int j = 0; j < 8; ++j) Bv[j] = __builtin_bit_cast(int, gb[40 + j][lane]);
        CSTEP(A[0], true);                                  // row 32 -> renorm
        #pragma unroll
        for (int j = 1; j < 8; ++j) CSTEP(A[j], false);    // rows 33..39
        #pragma unroll
        for (int j = 0; j < 8; ++j) A[j] = __builtin_bit_cast(int, gb[48 + j][lane]);
        #pragma unroll
        for (int j = 0; j < 8; ++j) CSTEP(Bv[j], false);   // rows 40..47
        #pragma unroll
        for (int j = 0; j < 8; ++j) Bv[j] = __builtin_bit_cast(int, gb[56 + j][lane]);
        #pragma unroll
        for (int j = 0; j < 8; ++j) CSTEP(A[j], false);    // rows 48..55
        #pragma unroll
        for (int j = 0; j < 8; ++j) CSTEP(Bv[j], false);   // rows 56..63
    };

    // ---- schedule: produce(k+1) overlaps consume(k); one barrier per chunk
    if (w != 0) produce(0);
    __syncthreads();
    if (w != 0) produce(1); else consume(gbuf[0], true);
    __syncthreads();
    for (int k = 1; k < 8; ++k) {
        if (w != 0) { if (k < 7) produce(k + 1); }
        else        consume(gbuf[k & 1], false);
        __syncthreads();
    }

    // epilogue
    if (w == 0) {
        Af[4 * lane + 0] = o0; Af[4 * lane + 1] = o1;
        Af[4 * lane + 2] = o2; Af[4 * lane + 3] = o3;
        if (lane == 63) Af[256] = o4;
    } else if (lane == 0) {
        accS[w] = acc;
    }
    __syncthreads();
    if (tid == 0) {
        const float fa = Af[2 * llen];
        const float fb = Af[2 * llen - 1];
        const float ls = ((accS[1] + accS[2]) + (accS[3] + accS[4]));
        loss[b] = -(__logf(fa + fb) + (float)Eacc * LN2F - ls);
    }
#undef CSTEP
#undef RENORM
}

// deterministic mean over B=256 losses
__global__ __launch_bounds__(256) void finalize(const float* __restrict__ loss,
                                                float* __restrict__ out) {
    __shared__ float red[256];
    const int tid = threadIdx.x;
    red[tid] = loss[tid];
    __syncthreads();
    for (int off = 128; off > 0; off >>= 1) {
        if (tid < off) red[tid] += red[tid + off];
        __syncthreads();
    }
    if (tid == 0) out[0] = red[0] * (1.0f / 256.0f);
}

extern "C" void kernel_launch(void* const* d_in, const int* in_sizes, int n_in,
                              void* d_out, int out_size, void* d_ws, size_t ws_size,
                              hipStream_t stream) {
    constexpr int B = 256;
    const int*   y_true = (const int*)d_in[0];
    const float* y_pred = (const float*)d_in[1];
    float* out  = (float*)d_out;
    float* lossbuf = (float*)d_ws;   // B floats

    ctc_fused<<<B, 320, 0, stream>>>(y_true, y_pred, lossbuf);
    finalize<<<1, 256, 0, stream>>>(lossbuf, out);
}